// Round 1
// baseline (101.258 us; speedup 1.0000x reference)
//
#include <hip/hip_runtime.h>

#define MDIM 4096
#define NDIM 1024
#define KDIM 512
#define BM 128
#define BN 128
#define BK 16
#define SA 132          // padded LDS stride for sA[k][m] (132%32=4 -> staging writes 2-way max)
#define TSTEPS 50

__global__ __launch_bounds__(256) void zero_tot_kernel(float* __restrict__ tot) {
    int i = blockIdx.x * 256 + threadIdx.x;
    if (i < MDIM) tot[i] = 0.0f;
}

__global__ __launch_bounds__(256) void snn_fused_kernel(
    const float* __restrict__ A,    // x [4096,512]
    const float* __restrict__ B,    // W_proj [512,1024]
    const float* __restrict__ bias, // b_proj [1024]
    float* __restrict__ agg,        // d_out[0 : 4096*1024]
    float* __restrict__ tot)        // d_out[4096*1024 : +4096]
{
    __shared__ __align__(16) float sA[BK * SA];  // [k][m], transposed A tile
    __shared__ __align__(16) float sB[BK * BN];  // [k][n]

    const int tid = threadIdx.x;
    const int tx  = tid & 15;
    const int ty  = tid >> 4;
    const int bn  = blockIdx.x & 7;    // NDIM/BN = 8
    const int bm  = blockIdx.x >> 3;   // MDIM/BM = 32
    const int m0  = bm * BM;
    const int n0  = bn * BN;

    // staging thread mapping
    const int arow = tid >> 2;   // 0..63 (and +64 for second half)
    const int akq  = tid & 3;    // which k-quad
    const int brow = tid >> 5;   // 0..7  (and +8)
    const int bcv  = tid & 31;   // col quad

    const float* gA0 = A + (size_t)(m0 + arow) * KDIM + akq * 4;
    const float* gA1 = A + (size_t)(m0 + arow + 64) * KDIM + akq * 4;
    const float* gB0 = B + (size_t)brow * NDIM + n0 + bcv * 4;
    const float* gB1 = B + (size_t)(brow + 8) * NDIM + n0 + bcv * 4;

    // prefetch chunk 0 into registers
    float4 pa0 = *(const float4*)gA0;
    float4 pa1 = *(const float4*)gA1;
    float4 pb0 = *(const float4*)gB0;
    float4 pb1 = *(const float4*)gB1;

    float acc[8][8];
    #pragma unroll
    for (int i = 0; i < 8; ++i)
        #pragma unroll
        for (int j = 0; j < 8; ++j) acc[i][j] = 0.0f;

    #pragma unroll 1
    for (int ch = 0; ch < KDIM / BK; ++ch) {
        __syncthreads();  // previous compute done; safe to overwrite LDS
        sA[(akq*4+0)*SA + arow]      = pa0.x;
        sA[(akq*4+1)*SA + arow]      = pa0.y;
        sA[(akq*4+2)*SA + arow]      = pa0.z;
        sA[(akq*4+3)*SA + arow]      = pa0.w;
        sA[(akq*4+0)*SA + arow + 64] = pa1.x;
        sA[(akq*4+1)*SA + arow + 64] = pa1.y;
        sA[(akq*4+2)*SA + arow + 64] = pa1.z;
        sA[(akq*4+3)*SA + arow + 64] = pa1.w;
        *(float4*)&sB[brow*BN + bcv*4]     = pb0;
        *(float4*)&sB[(brow+8)*BN + bcv*4] = pb1;
        __syncthreads();
        if (ch + 1 < KDIM / BK) {  // prefetch next chunk; latency hides under FMAs
            pa0 = *(const float4*)(gA0 + (ch + 1) * BK);
            pa1 = *(const float4*)(gA1 + (ch + 1) * BK);
            pb0 = *(const float4*)(gB0 + (size_t)(ch + 1) * BK * NDIM);
            pb1 = *(const float4*)(gB1 + (size_t)(ch + 1) * BK * NDIM);
        }
        #pragma unroll
        for (int k = 0; k < BK; ++k) {
            float4 ra0 = *(const float4*)&sA[k*SA + ty*4];        // broadcast reads
            float4 ra1 = *(const float4*)&sA[k*SA + ty*4 + 64];
            float4 rb0 = *(const float4*)&sB[k*BN + tx*4];
            float4 rb1 = *(const float4*)&sB[k*BN + tx*4 + 64];
            float av[8] = {ra0.x,ra0.y,ra0.z,ra0.w, ra1.x,ra1.y,ra1.z,ra1.w};
            float bv[8] = {rb0.x,rb0.y,rb0.z,rb0.w, rb1.x,rb1.y,rb1.z,rb1.w};
            #pragma unroll
            for (int i = 0; i < 8; ++i)
                #pragma unroll
                for (int j = 0; j < 8; ++j)
                    acc[i][j] = fmaf(av[i], bv[j], acc[i][j]);
        }
    }

    // bias
    float4 bb0 = *(const float4*)(bias + n0 + tx*4);
    float4 bb1 = *(const float4*)(bias + n0 + tx*4 + 64);
    float cb[8] = {bb0.x,bb0.y,bb0.z,bb0.w, bb1.x,bb1.y,bb1.z,bb1.w};

    // LIF recurrence: both layers identical -> simulate once.
    // spk_t == reset_{t+1}; fold reset into input select: mem = fma(beta, mem, sp ? c-1 : c)
    #pragma unroll
    for (int i = 0; i < 8; ++i) {
        float c[8], c1[8], mem[8];
        int cnt[8];
        bool sp[8];
        #pragma unroll
        for (int j = 0; j < 8; ++j) {
            c[j]   = acc[i][j] + cb[j];
            c1[j]  = c[j] - 1.0f;
            mem[j] = 0.0f;
            cnt[j] = 0;
            sp[j]  = false;
        }
        #pragma unroll 1
        for (int t = 0; t < TSTEPS; ++t) {
            #pragma unroll
            for (int j = 0; j < 8; ++j) {
                mem[j] = fmaf(0.95f, mem[j], sp[j] ? c1[j] : c[j]);
                sp[j]  = mem[j] > 1.0f;
                cnt[j] += sp[j] ? 1 : 0;
            }
        }
        const int row = m0 + ty*4 + (i & 3) + ((i >> 2) << 6);
        float4 o0 = make_float4((float)cnt[0], (float)cnt[1], (float)cnt[2], (float)cnt[3]);
        float4 o1 = make_float4((float)cnt[4], (float)cnt[5], (float)cnt[6], (float)cnt[7]);
        *(float4*)&agg[(size_t)row * NDIM + n0 + tx*4]      = o0;
        *(float4*)&agg[(size_t)row * NDIM + n0 + tx*4 + 64] = o1;
        // row partial for tot: integers <= 6400, exact in fp32; atomic order-independent
        int rs = cnt[0]+cnt[1]+cnt[2]+cnt[3]+cnt[4]+cnt[5]+cnt[6]+cnt[7];
        rs += __shfl_xor(rs, 1);
        rs += __shfl_xor(rs, 2);
        rs += __shfl_xor(rs, 4);
        rs += __shfl_xor(rs, 8);
        if (tx == 0) atomicAdd(&tot[row], 2.0f * (float)rs);
    }
}

extern "C" void kernel_launch(void* const* d_in, const int* in_sizes, int n_in,
                              void* d_out, int out_size, void* d_ws, size_t ws_size,
                              hipStream_t stream) {
    const float* x = (const float*)d_in[0];
    const float* W = (const float*)d_in[1];
    const float* b = (const float*)d_in[2];
    float* agg = (float*)d_out;
    float* tot = agg + (size_t)MDIM * NDIM;

    zero_tot_kernel<<<(MDIM + 255) / 256, 256, 0, stream>>>(tot);
    snn_fused_kernel<<<(MDIM / BM) * (NDIM / BN), 256, 0, stream>>>(x, W, b, agg, tot);
}

// Round 2
// 88.350 us; speedup vs baseline: 1.1461x; 1.1461x over previous
//
#include <hip/hip_runtime.h>

#define MDIM 4096
#define NDIM 1024
#define KDIM 512
#define BM 128
#define BN 128
#define BK 16
#define SA 132          // padded LDS stride for sA[k][m]: staging writes max 2-way (free)
#define TSTEPS 50
#define NCH (KDIM / BK)

__global__ __launch_bounds__(256) void zero_tot_kernel(float* __restrict__ tot) {
    int i = blockIdx.x * 256 + threadIdx.x;
    if (i < MDIM) tot[i] = 0.0f;
}

__global__ __launch_bounds__(1024) void snn_fused_kernel(
    const float* __restrict__ A,    // x [4096,512]
    const float* __restrict__ B,    // W_proj [512,1024]
    const float* __restrict__ bias, // b_proj [1024]
    float* __restrict__ agg,        // d_out[0 : 4096*1024]
    float* __restrict__ tot)        // d_out[4096*1024 : +4096]
{
    __shared__ __align__(16) float sA[BK * SA];  // [k][m] transposed A tile
    __shared__ __align__(16) float sB[BK * BN];  // [k][n]

    const int tid = threadIdx.x;
    const int tx  = tid & 31;   // col group: 32 x 4 cols = 128
    const int ty  = tid >> 5;   // row group: 32 x 4 rows = 128

    // XCD-aware swizzle (bijective: 256 = 8 XCDs x 32): each XCD gets 4
    // contiguous bm panels -> A panels fetched by exactly one XCD's L2.
    const int b   = blockIdx.x;
    const int swz = (b & 7) * 32 + (b >> 3);
    const int bn  = swz & 7;    // NDIM/BN = 8
    const int bm  = swz >> 3;   // MDIM/BM = 32
    const int m0  = bm * BM;
    const int n0  = bn * BN;

    // staging role split: waves 0-7 stage A (128x16 floats), waves 8-15 stage B (16x128)
    const bool isA = tid < 512;
    const int  u    = isA ? tid : tid - 512;
    const int  arow = u >> 2;          // 0..127
    const int  akq  = u & 3;           // k-quad
    const int  brow = u >> 5;          // 0..15
    const int  bc   = u & 31;          // col quad

    const float* gp;
    size_t gstep;
    if (isA) { gp = A + (size_t)(m0 + arow) * KDIM + akq * 4; gstep = BK; }
    else     { gp = B + (size_t)brow * NDIM + n0 + bc * 4;    gstep = (size_t)BK * NDIM; }

    float4 pref = *(const float4*)gp;
    gp += gstep;

    float acc[4][4];
    #pragma unroll
    for (int i = 0; i < 4; ++i)
        #pragma unroll
        for (int j = 0; j < 4; ++j) acc[i][j] = 0.0f;

    #pragma unroll 1
    for (int ch = 0; ch < NCH; ++ch) {
        __syncthreads();  // previous compute done; LDS safe to overwrite
        if (isA) {
            sA[(akq*4+0)*SA + arow] = pref.x;
            sA[(akq*4+1)*SA + arow] = pref.y;
            sA[(akq*4+2)*SA + arow] = pref.z;
            sA[(akq*4+3)*SA + arow] = pref.w;
        } else {
            *(float4*)&sB[brow*BN + bc*4] = pref;
        }
        __syncthreads();
        if (ch + 1 < NCH) {  // prefetch next chunk; hides under 256 FMAs
            pref = *(const float4*)gp;
            gp += gstep;
        }
        #pragma unroll
        for (int k = 0; k < BK; ++k) {
            // compile-time ds offsets: k*528 / k*512 -> zero per-k address VALU
            float4 ra = *(const float4*)&sA[k*SA + ty*4];
            float4 rb = *(const float4*)&sB[k*BN + tx*4];
            float av[4] = {ra.x, ra.y, ra.z, ra.w};
            float bv[4] = {rb.x, rb.y, rb.z, rb.w};
            #pragma unroll
            for (int i = 0; i < 4; ++i)
                #pragma unroll
                for (int j = 0; j < 4; ++j)
                    acc[i][j] = fmaf(av[i], bv[j], acc[i][j]);
        }
    }

    // bias for this thread's 4 cols
    float4 bb = *(const float4*)(bias + n0 + tx*4);
    float cb[4] = {bb.x, bb.y, bb.z, bb.w};

    // LIF recurrence: both layers identical (same zero init, same static input)
    // -> simulate once; agg = cnt, tot = 2 * row-sum(cnt).
    // spk_t == reset_{t+1}; fold reset: mem = fma(beta, mem, sp ? c-1 : c)
    #pragma unroll
    for (int i = 0; i < 4; ++i) {
        float c[4], c1[4], mem[4];
        int cnt[4];
        bool sp[4];
        #pragma unroll
        for (int j = 0; j < 4; ++j) {
            c[j]   = acc[i][j] + cb[j];
            c1[j]  = c[j] - 1.0f;
            mem[j] = 0.0f;
            cnt[j] = 0;
            sp[j]  = false;
        }
        #pragma unroll 1
        for (int t = 0; t < TSTEPS; ++t) {
            #pragma unroll
            for (int j = 0; j < 4; ++j) {
                mem[j] = fmaf(0.95f, mem[j], sp[j] ? c1[j] : c[j]);
                sp[j]  = mem[j] > 1.0f;
                cnt[j] += sp[j] ? 1 : 0;
            }
        }
        const int row = m0 + ty*4 + i;
        float4 o = make_float4((float)cnt[0], (float)cnt[1], (float)cnt[2], (float)cnt[3]);
        *(float4*)&agg[(size_t)row * NDIM + n0 + tx*4] = o;
        // tot row partial: integer counts (<=6400/row) exact in fp32; order-independent
        int rs = cnt[0] + cnt[1] + cnt[2] + cnt[3];
        rs += __shfl_xor(rs, 1);
        rs += __shfl_xor(rs, 2);
        rs += __shfl_xor(rs, 4);
        rs += __shfl_xor(rs, 8);
        rs += __shfl_xor(rs, 16);   // reduce within each 32-lane half (full tx range)
        if (tx == 0) atomicAdd(&tot[row], 2.0f * (float)rs);
    }
}

extern "C" void kernel_launch(void* const* d_in, const int* in_sizes, int n_in,
                              void* d_out, int out_size, void* d_ws, size_t ws_size,
                              hipStream_t stream) {
    const float* x = (const float*)d_in[0];
    const float* W = (const float*)d_in[1];
    const float* b = (const float*)d_in[2];
    float* agg = (float*)d_out;
    float* tot = agg + (size_t)MDIM * NDIM;

    zero_tot_kernel<<<(MDIM + 255) / 256, 256, 0, stream>>>(tot);
    snn_fused_kernel<<<(MDIM / BM) * (NDIM / BN), 1024, 0, stream>>>(x, W, b, agg, tot);
}